// Round 1
// baseline (1713.143 us; speedup 1.0000x reference)
//
#include <hip/hip_runtime.h>
#include <math.h>

// Problem: B=1024, S=256, D=256, all fp32.
// logp[b,s] = -0.5*(D*log(2pi) + logdet_s + ||L_s^{-1}(x_b - mu_s)||^2)
// sigma_s = sp_s^T sp_s + ridge_s*I,  ridge_s = 0.01*||sp_s||_F^2/D,  L = chol(sigma)
//
// ws layout: one 256x256 fp32 matrix per s (64 MB total). Packing in per-s matrix M:
//   ridge_s  at M[0*256+128]                      (K1 writes, K2 reads, clobbered later)
//   logdet_s at M[0*256+64]                       (K3 writes at end, K4 reads)
//   invD_kb (64x64, inverse of kb-th diagonal Cholesky block) stored in the
//   strictly-upper-right 128x128 quadrant: rows (kb/2)*64.., cols 128+(kb%2)*64..
//   (that quadrant is never touched by gram/panel/trailing writes)

#define LOG2PI_D 470.4965290007924f  // 256 * log(2*pi)

__global__ __launch_bounds__(256) void k_ridge(const float* __restrict__ sp,
                                               float* __restrict__ L) {
  int s = blockIdx.x;
  const float4* p = (const float4*)(sp + (size_t)s * 65536);
  float acc = 0.f;
#pragma unroll 4
  for (int it = 0; it < 64; ++it) {
    float4 v = p[threadIdx.x + it * 256];
    acc += v.x * v.x + v.y * v.y + v.z * v.z + v.w * v.w;
  }
  for (int off = 32; off > 0; off >>= 1) acc += __shfl_down(acc, off, 64);
  __shared__ float red[4];
  if ((threadIdx.x & 63) == 0) red[threadIdx.x >> 6] = acc;
  __syncthreads();
  if (threadIdx.x == 0) {
    float t = red[0] + red[1] + red[2] + red[3];
    L[(size_t)s * 65536 + 128] = 0.01f * t / 256.0f;
  }
}

// Gram: C = sp^T sp (+ ridge on diag). 128x128 output blocks, lower pairs only:
// (bi,bj) in {(0,0),(1,0),(1,1)}. 256 thr, 8x8 register tiles.
__global__ __launch_bounds__(256) void k_gram(const float* __restrict__ sp,
                                              float* __restrict__ L) {
  const int pi_[3] = {0, 1, 1};
  const int pj_[3] = {0, 0, 1};
  int p = blockIdx.x;
  int s = blockIdx.y;
  int bi = pi_[p] * 128, bj = pj_[p] * 128;
  const float* A = sp + (size_t)s * 65536;
  float* C = L + (size_t)s * 65536;
  __shared__ float As[32][132];
  __shared__ float Bs[32][132];
  float acc[8][8] = {};
  int ty = threadIdx.x / 16, tx = threadIdx.x % 16;
  int lc4 = threadIdx.x % 32, lrb = threadIdx.x / 32;
  float ridge = C[128];  // written by k_ridge; never written by k_gram
  for (int k0 = 0; k0 < 256; k0 += 32) {
    __syncthreads();
#pragma unroll
    for (int pass = 0; pass < 4; ++pass) {
      int r = lrb + pass * 8;
      *(float4*)&As[r][lc4 * 4] = *(const float4*)(A + (size_t)(k0 + r) * 256 + bi + lc4 * 4);
      *(float4*)&Bs[r][lc4 * 4] = *(const float4*)(A + (size_t)(k0 + r) * 256 + bj + lc4 * 4);
    }
    __syncthreads();
#pragma unroll
    for (int kk = 0; kk < 32; ++kk) {
      float a[8], b[8];
      *(float4*)&a[0] = *(float4*)&As[kk][ty * 8];
      *(float4*)&a[4] = *(float4*)&As[kk][ty * 8 + 4];
      *(float4*)&b[0] = *(float4*)&Bs[kk][tx * 8];
      *(float4*)&b[4] = *(float4*)&Bs[kk][tx * 8 + 4];
#pragma unroll
      for (int i = 0; i < 8; ++i)
#pragma unroll
        for (int j = 0; j < 8; ++j) acc[i][j] += a[i] * b[j];
    }
  }
#pragma unroll
  for (int i = 0; i < 8; ++i) {
    int d = bi + ty * 8 + i;
#pragma unroll
    for (int j = 0; j < 8; ++j) {
      int e = bj + tx * 8 + j;
      if (d == e) acc[i][j] += ridge;
    }
    *(float4*)(C + (size_t)d * 256 + bj + tx * 8) = *(float4*)&acc[i][0];
    *(float4*)(C + (size_t)d * 256 + bj + tx * 8 + 4) = *(float4*)&acc[i][4];
  }
}

// Blocked right-looking Cholesky, one workgroup per s. 64-wide panels in LDS,
// trailing updates read-modify-write global. Also emits invD_kb and logdet.
// dyn LDS: P[256][68] + PT[64][264] + W[64][68]  = 154,624 B
__global__ __launch_bounds__(256) void k_chol(float* __restrict__ L) {
  extern __shared__ float lds[];
  float* P = lds;               // [256][68] panel (row-major, pad 68)
  float* PT = lds + 256 * 68;   // [64][264] transposed panel
  float* W = PT + 64 * 264;     // [64][68] inv of diagonal block
  int s = blockIdx.x;
  float* M = L + (size_t)s * 65536;
  int tid = threadIdx.x;
  float logacc = 0.f;

  for (int kb = 0; kb < 4; ++kb) {
    int R = 256 - kb * 64;
    // load panel rows 0..R-1 (global rows kb*64..), cols kb*64..+64
    {
      int k4 = tid % 16, rb = tid / 16;
      for (int r = rb; r < R; r += 16)
        *(float4*)&P[r * 68 + k4 * 4] =
            *(const float4*)(M + (size_t)(kb * 64 + r) * 256 + kb * 64 + k4 * 4);
    }
    __syncthreads();
    // factor panel (64 sequential columns)
    for (int c = 0; c < 64; ++c) {
      if (tid == 0) {
        float g = P[c * 68 + c];
        P[c * 68 + c] = sqrtf(g);
        logacc += logf(g);
      }
      __syncthreads();
      float dinv = 1.0f / P[c * 68 + c];
      for (int r = c + 1 + tid; r < R; r += 256) P[r * 68 + c] *= dinv;
      __syncthreads();
      int eo = tid % 64, ro = tid / 64;
      int e = c + 1 + eo;
      if (e < 64) {
        float le = P[e * 68 + c];
        for (int r = c + 1 + ro; r < R; r += 4) P[r * 68 + e] -= P[r * 68 + c] * le;
      }
      __syncthreads();
    }
    // write panel back
    {
      int k4 = tid % 16, rb = tid / 16;
      for (int r = rb; r < R; r += 16)
        *(float4*)(M + (size_t)(kb * 64 + r) * 256 + kb * 64 + k4 * 4) =
            *(float4*)&P[r * 68 + k4 * 4];
    }
    // build transposed panel for trailing GEMMs
    for (int r = tid; r < R; r += 256)
#pragma unroll 8
      for (int k = 0; k < 64; ++k) PT[k * 264 + r] = P[r * 68 + k];
    __syncthreads();
    // trailing update: A[ti,tj] -= P_i P_j^T  (ti>=tj>kb), 4x4 reg tiles
    {
      int ty = tid / 16, tx = tid % 16;
      for (int ti = kb + 1; ti < 4; ++ti)
        for (int tj = kb + 1; tj <= ti; ++tj) {
          int oi = (ti - kb) * 64, oj = (tj - kb) * 64;
          float acc[4][4];
#pragma unroll
          for (int rr = 0; rr < 4; ++rr) {
            float4 v = *(const float4*)(M + (size_t)(ti * 64 + ty * 4 + rr) * 256 + tj * 64 + tx * 4);
            acc[rr][0] = v.x; acc[rr][1] = v.y; acc[rr][2] = v.z; acc[rr][3] = v.w;
          }
#pragma unroll 4
          for (int k = 0; k < 64; ++k) {
            float a[4], b[4];
            *(float4*)a = *(float4*)&PT[k * 264 + oi + ty * 4];
            *(float4*)b = *(float4*)&PT[k * 264 + oj + tx * 4];
#pragma unroll
            for (int rr = 0; rr < 4; ++rr)
#pragma unroll
              for (int cc = 0; cc < 4; ++cc) acc[rr][cc] -= a[rr] * b[cc];
          }
#pragma unroll
          for (int rr = 0; rr < 4; ++rr) {
            float4 v = make_float4(acc[rr][0], acc[rr][1], acc[rr][2], acc[rr][3]);
            *(float4*)(M + (size_t)(ti * 64 + ty * 4 + rr) * 256 + tj * 64 + tx * 4) = v;
          }
        }
    }
    __syncthreads();
    // invert diagonal block (lower-tri 64x64 in P[0..63][0..63]) -> W
    if (tid < 64) {
      int c = tid;
      for (int r = 0; r < c; ++r) W[r * 68 + c] = 0.f;
      W[c * 68 + c] = 1.0f / P[c * 68 + c];
      for (int r = c + 1; r < 64; ++r) {
        float a0 = 0, a1 = 0, a2 = 0, a3 = 0;
        int k = c;
        for (; k + 3 < r; k += 4) {
          a0 += P[r * 68 + k] * W[k * 68 + c];
          a1 += P[r * 68 + k + 1] * W[(k + 1) * 68 + c];
          a2 += P[r * 68 + k + 2] * W[(k + 2) * 68 + c];
          a3 += P[r * 68 + k + 3] * W[(k + 3) * 68 + c];
        }
        for (; k < r; ++k) a0 += P[r * 68 + k] * W[k * 68 + c];
        W[r * 68 + c] = -(a0 + a1 + a2 + a3) / P[r * 68 + r];
      }
    }
    __syncthreads();
    // store invD_kb into upper-right quadrant
    {
      int k4 = tid % 16, rb = tid / 16;
      for (int r = rb; r < 64; r += 16)
        *(float4*)(M + (size_t)((kb / 2) * 64 + r) * 256 + 128 + (kb % 2) * 64 + k4 * 4) =
            *(float4*)&W[r * 68 + k4 * 4];
    }
    __syncthreads();
  }
  if (tid == 0) M[64] = logacc;  // logdet = sum log(diag^2) = 2*sum log(L_ii)
}

// Fused blocked forward substitution + Mahalanobis + output.
// One block per (s, 64-b tile). y_i = invD_i*(diff_i - sum_j L[i,j] y_j), maha += y^2.
// dyn LDS: Y[256][64] + St[64][68] + Mu[256] + mbuf[16][64] = 88,064 B
__global__ __launch_bounds__(256) void k_maha(const float* __restrict__ x,
                                              const float* __restrict__ mu_p,
                                              const float* __restrict__ L,
                                              float* __restrict__ out) {
  extern __shared__ float lds[];
  float* Y = lds;                  // [256][64] persistent y (d-major, 64 b cols)
  float* St = Y + 256 * 64;        // [64][68] staging (X panel / L^T tile / invD^T tile)
  float* Mu = St + 64 * 68;        // [256]
  float* mbuf = Mu + 256;          // [16][64]
  int s = blockIdx.y;
  int b0 = blockIdx.x * 64;
  const float* M = L + (size_t)s * 65536;
  int tid = threadIdx.x;
  int ty = tid / 16, tx = tid % 16;
  if (tid < 64) *(float4*)&Mu[tid * 4] = *(const float4*)(mu_p + (size_t)s * 256 + tid * 4);
  float macc[4] = {0.f, 0.f, 0.f, 0.f};
  __syncthreads();

  for (int i = 0; i < 4; ++i) {
    // stage x panel: St[c][k] = x[b0+c][i*64+k]
    {
      int k4 = tid % 16, cb = tid / 16;
      for (int c = cb; c < 64; c += 16)
        *(float4*)&St[c * 68 + k4 * 4] =
            *(const float4*)(x + (size_t)(b0 + c) * 256 + i * 64 + k4 * 4);
    }
    __syncthreads();
    float acc[4][4];
#pragma unroll
    for (int rr = 0; rr < 4; ++rr) {
      float m = Mu[i * 64 + ty * 4 + rr];
#pragma unroll
      for (int cc = 0; cc < 4; ++cc) acc[rr][cc] = St[(tx * 4 + cc) * 68 + ty * 4 + rr] - m;
    }
    __syncthreads();
    // r_i -= L[i,j] * y_j
    for (int j = 0; j < i; ++j) {
      {
        int k4 = tid % 16, rb = tid / 16;
        for (int r = rb; r < 64; r += 16) {
          float4 v = *(const float4*)(M + (size_t)(i * 64 + r) * 256 + j * 64 + k4 * 4);
          St[(k4 * 4 + 0) * 68 + r] = v.x;
          St[(k4 * 4 + 1) * 68 + r] = v.y;
          St[(k4 * 4 + 2) * 68 + r] = v.z;
          St[(k4 * 4 + 3) * 68 + r] = v.w;
        }
      }
      __syncthreads();
#pragma unroll 4
      for (int k = 0; k < 64; ++k) {
        float a[4], b[4];
        *(float4*)a = *(float4*)&St[k * 68 + ty * 4];
        *(float4*)b = *(float4*)&Y[(size_t)(j * 64 + k) * 64 + tx * 4];
#pragma unroll
        for (int rr = 0; rr < 4; ++rr)
#pragma unroll
          for (int cc = 0; cc < 4; ++cc) acc[rr][cc] -= a[rr] * b[cc];
      }
      __syncthreads();
    }
    // park r_i in Y[i] region as temp; stage invD_i transposed
#pragma unroll
    for (int rr = 0; rr < 4; ++rr)
      *(float4*)&Y[(size_t)(i * 64 + ty * 4 + rr) * 64 + tx * 4] =
          make_float4(acc[rr][0], acc[rr][1], acc[rr][2], acc[rr][3]);
    {
      int k4 = tid % 16, rb = tid / 16;
      for (int r = rb; r < 64; r += 16) {
        float4 v = *(const float4*)(M + (size_t)((i / 2) * 64 + r) * 256 + 128 + (i % 2) * 64 + k4 * 4);
        St[(k4 * 4 + 0) * 68 + r] = v.x;
        St[(k4 * 4 + 1) * 68 + r] = v.y;
        St[(k4 * 4 + 2) * 68 + r] = v.z;
        St[(k4 * 4 + 3) * 68 + r] = v.w;
      }
    }
    __syncthreads();
    // y_i = invD_i * r_i
    float yv[4][4] = {};
#pragma unroll 4
    for (int k = 0; k < 64; ++k) {
      float a[4], b[4];
      *(float4*)a = *(float4*)&St[k * 68 + ty * 4];
      *(float4*)b = *(float4*)&Y[(size_t)(i * 64 + k) * 64 + tx * 4];
#pragma unroll
      for (int rr = 0; rr < 4; ++rr)
#pragma unroll
        for (int cc = 0; cc < 4; ++cc) yv[rr][cc] += a[rr] * b[cc];
    }
    __syncthreads();
#pragma unroll
    for (int rr = 0; rr < 4; ++rr) {
      *(float4*)&Y[(size_t)(i * 64 + ty * 4 + rr) * 64 + tx * 4] =
          make_float4(yv[rr][0], yv[rr][1], yv[rr][2], yv[rr][3]);
#pragma unroll
      for (int cc = 0; cc < 4; ++cc) macc[cc] += yv[rr][cc] * yv[rr][cc];
    }
    __syncthreads();
  }
  *(float4*)&mbuf[ty * 64 + tx * 4] = make_float4(macc[0], macc[1], macc[2], macc[3]);
  __syncthreads();
  if (tid < 64) {
    float mh = 0.f;
#pragma unroll
    for (int t2 = 0; t2 < 16; ++t2) mh += mbuf[t2 * 64 + tid];
    float logdet = M[64];
    out[(size_t)(b0 + tid) * 256 + s] = -0.5f * (LOG2PI_D + logdet + mh);
  }
}

extern "C" void kernel_launch(void* const* d_in, const int* in_sizes, int n_in,
                              void* d_out, int out_size, void* d_ws, size_t ws_size,
                              hipStream_t stream) {
  const float* x = (const float*)d_in[0];       // (1024, 256)
  const float* mu = (const float*)d_in[1];      // (256, 1, 256)
  const float* sp = (const float*)d_in[2];      // (256, 1, 256, 256)
  float* out = (float*)d_out;                   // (1024, 256) fp32
  float* L = (float*)d_ws;                      // 64 MB scratch

  const int chol_lds = (256 * 68 + 64 * 264 + 64 * 68) * 4;       // 154,624 B
  const int maha_lds = (256 * 64 + 64 * 68 + 256 + 16 * 64) * 4;  // 88,064 B
  (void)hipFuncSetAttribute((const void*)k_chol,
                            hipFuncAttributeMaxDynamicSharedMemorySize, chol_lds);
  (void)hipFuncSetAttribute((const void*)k_maha,
                            hipFuncAttributeMaxDynamicSharedMemorySize, maha_lds);

  k_ridge<<<256, 256, 0, stream>>>(sp, L);
  k_gram<<<dim3(3, 256), 256, 0, stream>>>(sp, L);
  k_chol<<<256, 256, chol_lds, stream>>>(L);
  k_maha<<<dim3(16, 256), 256, maha_lds, stream>>>(x, mu, L, out);
}

// Round 2
// 940.236 us; speedup vs baseline: 1.8220x; 1.8220x over previous
//
#include <hip/hip_runtime.h>
#include <math.h>

// B=1024, S=256, D=256 fp32.
// logp[b,s] = -0.5*(D*log2pi + logdet_s + ||L_s^{-1}(x_b-mu_s)||^2)
//
// ws: one 256x256 fp32 matrix M per s (64 MB total). Lifecycle of M:
//   gram (+ridge) -> lower/diag blocks hold sigma
//   panel(kb): factors diag block kb, writes invD_kb^T OVER diag block kb,
//              TRSMs sub-panel, writes L(i,kb) to lower AND L^T to upper (kb,i)
//   trail(kb): C(ti,tj) -= L_i L_j^T  reading the coalesced upper copies
//   maha: reads ONLY upper (L^T) + diag (invD^T) blocks -> straight-copy staging
//   logdet derived in maha: logdet = -2 * sum_k log(invD[k][k])

#define LOG2PI_D 470.4965290007924f  // 256*log(2*pi)

__device__ __forceinline__ unsigned bf16rtn(float f) {
  unsigned u = __float_as_uint(f);
  return (u + 0x7FFFu + ((u >> 16) & 1u)) >> 16;
}
__device__ __forceinline__ unsigned pack2(float f0, float f1) {
  return bf16rtn(f0) | (bf16rtn(f1) << 16);
}

__global__ __launch_bounds__(256) void k_ridge(const float* __restrict__ sp,
                                               float* __restrict__ L) {
  int s = blockIdx.x;
  const float4* p = (const float4*)(sp + (size_t)s * 65536);
  float acc = 0.f;
#pragma unroll 4
  for (int it = 0; it < 64; ++it) {
    float4 v = p[threadIdx.x + it * 256];
    acc += v.x * v.x + v.y * v.y + v.z * v.z + v.w * v.w;
  }
  for (int off = 32; off > 0; off >>= 1) acc += __shfl_down(acc, off, 64);
  __shared__ float red[4];
  if ((threadIdx.x & 63) == 0) red[threadIdx.x >> 6] = acc;
  __syncthreads();
  if (threadIdx.x == 0) {
    float t = red[0] + red[1] + red[2] + red[3];
    L[(size_t)s * 65536 + 128] = 0.01f * t / 256.0f;
  }
}

// Gram: C = sp^T sp (+ridge diag). 128x128 lower blocks only.
__global__ __launch_bounds__(256) void k_gram(const float* __restrict__ sp,
                                              float* __restrict__ L) {
  const int pi_[3] = {0, 1, 1};
  const int pj_[3] = {0, 0, 1};
  int p = blockIdx.x, s = blockIdx.y;
  int bi = pi_[p] * 128, bj = pj_[p] * 128;
  const float* A = sp + (size_t)s * 65536;
  float* C = L + (size_t)s * 65536;
  __shared__ float As[32][132];
  __shared__ float Bs[32][132];
  float acc[8][8] = {};
  int ty = threadIdx.x / 16, tx = threadIdx.x % 16;
  int lc4 = threadIdx.x % 32, lrb = threadIdx.x / 32;
  float ridge = C[128];
  for (int k0 = 0; k0 < 256; k0 += 32) {
    __syncthreads();
#pragma unroll
    for (int pass = 0; pass < 4; ++pass) {
      int r = lrb + pass * 8;
      *(float4*)&As[r][lc4 * 4] = *(const float4*)(A + (size_t)(k0 + r) * 256 + bi + lc4 * 4);
      *(float4*)&Bs[r][lc4 * 4] = *(const float4*)(A + (size_t)(k0 + r) * 256 + bj + lc4 * 4);
    }
    __syncthreads();
#pragma unroll
    for (int kk = 0; kk < 32; ++kk) {
      float a[8], b[8];
      *(float4*)&a[0] = *(float4*)&As[kk][ty * 8];
      *(float4*)&a[4] = *(float4*)&As[kk][ty * 8 + 4];
      *(float4*)&b[0] = *(float4*)&Bs[kk][tx * 8];
      *(float4*)&b[4] = *(float4*)&Bs[kk][tx * 8 + 4];
#pragma unroll
      for (int i = 0; i < 8; ++i)
#pragma unroll
        for (int j = 0; j < 8; ++j) acc[i][j] += a[i] * b[j];
    }
  }
#pragma unroll
  for (int i = 0; i < 8; ++i) {
    int d = bi + ty * 8 + i;
#pragma unroll
    for (int j = 0; j < 8; ++j) {
      int e = bj + tx * 8 + j;
      if (d == e) acc[i][j] += ridge;
    }
    *(float4*)(C + (size_t)d * 256 + bj + tx * 8) = *(float4*)&acc[i][0];
    *(float4*)(C + (size_t)d * 256 + bj + tx * 8 + 4) = *(float4*)&acc[i][4];
  }
}

// Panel kb: factor diag, invert it (-> invD^T over diag block), TRSM sub-panel
// via GEMM with invD^T, write L blocks to lower AND transposed to upper (kb,i).
// dyn LDS: 4 * 64*68*4 = 69,632 B
__global__ __launch_bounds__(256) void k_panel(float* __restrict__ L, int kb) {
  extern __shared__ float lds[];
  float* P = lds;              // [64][68] diag block / factored L_d
  float* W = lds + 64 * 68;    // [64][68] invD (lower)
  float* WT = lds + 2 * 64 * 68;  // [64][68] WT[k][c] = W[c][k]
  float* T = lds + 3 * 64 * 68;   // [64][68] A_sub^T staging, then C^T
  int s = blockIdx.x;
  float* M = L + (size_t)s * 65536;
  int tid = threadIdx.x;
  int k4 = tid & 15, rb = tid >> 4;
  int ty = tid >> 4, tx = tid & 15;
  int base = kb * 64;

  for (int r = rb; r < 64; r += 16)
    *(float4*)&P[r * 68 + k4 * 4] = *(const float4*)(M + (size_t)(base + r) * 256 + base + k4 * 4);
  __syncthreads();
  // factor 64x64 (upper-in-block entries are write-only garbage, never read)
  for (int c = 0; c < 64; ++c) {
    if (tid == 0) P[c * 68 + c] = sqrtf(P[c * 68 + c]);
    __syncthreads();
    float dinv = 1.0f / P[c * 68 + c];
    int r = c + 1 + tid;
    if (r < 64) P[r * 68 + c] *= dinv;
    __syncthreads();
    int eo = tid & 63, ro = tid >> 6;
    int e = c + 1 + eo;
    if (e < 64) {
      float le = P[e * 68 + c];
      for (int r2 = c + 1 + ro; r2 < 64; r2 += 4) P[r2 * 68 + e] -= P[r2 * 68 + c] * le;
    }
    __syncthreads();
  }
  // invert diag block (lower-tri), zeros in upper
  if (tid < 64) {
    int c = tid;
    for (int r = 0; r < c; ++r) W[r * 68 + c] = 0.f;
    W[c * 68 + c] = 1.0f / P[c * 68 + c];
    for (int r = c + 1; r < 64; ++r) {
      float a = 0.f;
      for (int k = c; k < r; ++k) a += P[r * 68 + k] * W[k * 68 + c];
      W[r * 68 + c] = -a / P[r * 68 + r];
    }
  }
  __syncthreads();
  // WT = W^T; write invD^T over diag block
  for (int c = rb; c < 64; c += 16) {
    float4 v = *(float4*)&W[c * 68 + k4 * 4];
    WT[(k4 * 4 + 0) * 68 + c] = v.x;
    WT[(k4 * 4 + 1) * 68 + c] = v.y;
    WT[(k4 * 4 + 2) * 68 + c] = v.z;
    WT[(k4 * 4 + 3) * 68 + c] = v.w;
  }
  __syncthreads();
  for (int r = rb; r < 64; r += 16)
    *(float4*)(M + (size_t)(base + r) * 256 + base + k4 * 4) = *(float4*)&WT[r * 68 + k4 * 4];
  // sub-panel: L_sub = A_sub * invD^T  (GEMM, no barriers in k-loop)
  int nrt = 3 - kb;
  for (int rt = 0; rt < nrt; ++rt) {
    int g0 = base + 64 + rt * 64;
    __syncthreads();  // protect T reuse
    for (int r = rb; r < 64; r += 16) {
      float4 v = *(const float4*)(M + (size_t)(g0 + r) * 256 + base + k4 * 4);
      T[(k4 * 4 + 0) * 68 + r] = v.x;
      T[(k4 * 4 + 1) * 68 + r] = v.y;
      T[(k4 * 4 + 2) * 68 + r] = v.z;
      T[(k4 * 4 + 3) * 68 + r] = v.w;
    }
    __syncthreads();
    float acc[4][4] = {};
    for (int k = 0; k < 64; ++k) {
      float a[4], b[4];
      *(float4*)a = *(float4*)&T[k * 68 + ty * 4];
      *(float4*)b = *(float4*)&WT[k * 68 + tx * 4];
#pragma unroll
      for (int i = 0; i < 4; ++i)
#pragma unroll
        for (int j = 0; j < 4; ++j) acc[i][j] += a[i] * b[j];
    }
    __syncthreads();  // T reads done before CT overwrite
#pragma unroll
    for (int i = 0; i < 4; ++i)
      *(float4*)(M + (size_t)(g0 + ty * 4 + i) * 256 + base + tx * 4) =
          make_float4(acc[i][0], acc[i][1], acc[i][2], acc[i][3]);
#pragma unroll
    for (int i = 0; i < 4; ++i)
#pragma unroll
      for (int j = 0; j < 4; ++j) T[(tx * 4 + j) * 68 + ty * 4 + i] = acc[i][j];
    __syncthreads();
    for (int r = rb; r < 64; r += 16)
      *(float4*)(M + (size_t)(base + r) * 256 + g0 + k4 * 4) = *(float4*)&T[r * 68 + k4 * 4];
  }
}

// Trailing update: C(ti,tj) -= L_i L_j^T, reading coalesced upper L^T copies.
// dyn LDS: 2 * 64*68*4 = 34,816 B
__global__ __launch_bounds__(256) void k_trail(float* __restrict__ L, int kb) {
  extern __shared__ float lds[];
  float* Pi = lds;           // Pi[k][r] = L(ti,kb)[r][k]
  float* Pj = lds + 64 * 68;
  int p = blockIdx.x, s = blockIdx.y;
  int ti = 0, tj = 0, cnt = 0;
  for (int a = kb + 1; a < 4; ++a)
    for (int b = kb + 1; b <= a; ++b) {
      if (cnt == p) { ti = a; tj = b; }
      ++cnt;
    }
  float* M = L + (size_t)s * 65536;
  int tid = threadIdx.x, k4 = tid & 15, rb = tid >> 4;
  int ty = tid >> 4, tx = tid & 15;
  int base = kb * 64;
  for (int k = rb; k < 64; k += 16) {
    *(float4*)&Pi[k * 68 + k4 * 4] = *(const float4*)(M + (size_t)(base + k) * 256 + ti * 64 + k4 * 4);
    *(float4*)&Pj[k * 68 + k4 * 4] = *(const float4*)(M + (size_t)(base + k) * 256 + tj * 64 + k4 * 4);
  }
  float acc[4][4];
#pragma unroll
  for (int i = 0; i < 4; ++i)
    *(float4*)&acc[i][0] = *(const float4*)(M + (size_t)(ti * 64 + ty * 4 + i) * 256 + tj * 64 + tx * 4);
  __syncthreads();
  for (int k = 0; k < 64; ++k) {
    float a[4], b[4];
    *(float4*)a = *(float4*)&Pi[k * 68 + ty * 4];
    *(float4*)b = *(float4*)&Pj[k * 68 + tx * 4];
#pragma unroll
    for (int i = 0; i < 4; ++i)
#pragma unroll
      for (int j = 0; j < 4; ++j) acc[i][j] -= a[i] * b[j];
  }
#pragma unroll
  for (int i = 0; i < 4; ++i)
    *(float4*)(M + (size_t)(ti * 64 + ty * 4 + i) * 256 + tj * 64 + tx * 4) =
        make_float4(acc[i][0], acc[i][1], acc[i][2], acc[i][3]);
}

// Fused blocked forward substitution + Mahalanobis + logdet + output.
// y history packed bf16. All L/invD staging = straight coalesced copies.
// dyn LDS: Yb 34,816 + St 17,408 + Red 1,040 = 53,264 B -> 3 blocks/CU
__global__ __launch_bounds__(256) void k_maha(const float* __restrict__ x,
                                              const float* __restrict__ mu_p,
                                              const float* __restrict__ L,
                                              float* __restrict__ out) {
  extern __shared__ float lds[];
  unsigned* Yb = (unsigned*)lds;   // [256][34] packed bf16 pairs (68 bf16 cols, use 64)
  float* St = lds + 256 * 34;      // [64][68]
  float* Red = St + 64 * 68;       // [257]
  int s = blockIdx.y, b0 = blockIdx.x * 64;
  const float* M = L + (size_t)s * 65536;
  int tid = threadIdx.x, ty = tid >> 4, tx = tid & 15;
  int k4 = tid & 15, rb = tid >> 4;
  float macc[4] = {0.f, 0.f, 0.f, 0.f};
  float ldacc = 0.f;

  for (int i = 0; i < 4; ++i) {
    // diff tile straight from global (x/mu are L2-hot)
    float4 xm = *(const float4*)(mu_p + (size_t)s * 256 + i * 64 + ty * 4);
    float acc[4][4];
#pragma unroll
    for (int j = 0; j < 4; ++j) {
      float4 xv = *(const float4*)(x + (size_t)(b0 + tx * 4 + j) * 256 + i * 64 + ty * 4);
      acc[0][j] = xv.x - xm.x;
      acc[1][j] = xv.y - xm.y;
      acc[2][j] = xv.z - xm.z;
      acc[3][j] = xv.w - xm.w;
    }
    // r_i -= L[i][j] * y_j  (a-operand staged from upper L^T copy)
    for (int j = 0; j < i; ++j) {
      __syncthreads();
      for (int k = rb; k < 64; k += 16)
        *(float4*)&St[k * 68 + k4 * 4] =
            *(const float4*)(M + (size_t)(j * 64 + k) * 256 + i * 64 + k4 * 4);
      __syncthreads();
      for (int k = 0; k < 64; ++k) {
        float a[4], b[4];
        *(float4*)a = *(float4*)&St[k * 68 + ty * 4];
        uint2 u = *(uint2*)&Yb[(j * 64 + k) * 34 + tx * 2];
        b[0] = __uint_as_float(u.x << 16);
        b[1] = __uint_as_float(u.x & 0xFFFF0000u);
        b[2] = __uint_as_float(u.y << 16);
        b[3] = __uint_as_float(u.y & 0xFFFF0000u);
#pragma unroll
        for (int r = 0; r < 4; ++r) {
          acc[r][0] -= a[r] * b[0];
          acc[r][1] -= a[r] * b[1];
          acc[r][2] -= a[r] * b[2];
          acc[r][3] -= a[r] * b[3];
        }
      }
    }
    // park r_i (bf16) in stage-i region; stage invD_i^T (diag block holds it)
    __syncthreads();
#pragma unroll
    for (int r = 0; r < 4; ++r) {
      uint2 u;
      u.x = pack2(acc[r][0], acc[r][1]);
      u.y = pack2(acc[r][2], acc[r][3]);
      *(uint2*)&Yb[(size_t)(i * 64 + ty * 4 + r) * 34 + tx * 2] = u;
    }
    for (int k = rb; k < 64; k += 16)
      *(float4*)&St[k * 68 + k4 * 4] =
          *(const float4*)(M + (size_t)(i * 64 + k) * 256 + i * 64 + k4 * 4);
    __syncthreads();
    if (tid < 64) ldacc += logf(St[tid * 68 + tid]);  // diag(invD) = 1/L_kk
    // y_i = invD_i * r_i
    float yv[4][4] = {};
    for (int k = 0; k < 64; ++k) {
      float a[4], b[4];
      *(float4*)a = *(float4*)&St[k * 68 + ty * 4];
      uint2 u = *(uint2*)&Yb[(i * 64 + k) * 34 + tx * 2];
      b[0] = __uint_as_float(u.x << 16);
      b[1] = __uint_as_float(u.x & 0xFFFF0000u);
      b[2] = __uint_as_float(u.y << 16);
      b[3] = __uint_as_float(u.y & 0xFFFF0000u);
#pragma unroll
      for (int r = 0; r < 4; ++r) {
        yv[r][0] += a[r] * b[0];
        yv[r][1] += a[r] * b[1];
        yv[r][2] += a[r] * b[2];
        yv[r][3] += a[r] * b[3];
      }
    }
    __syncthreads();  // park reads done before overwrite with y
#pragma unroll
    for (int r = 0; r < 4; ++r) {
      uint2 u;
      u.x = pack2(yv[r][0], yv[r][1]);
      u.y = pack2(yv[r][2], yv[r][3]);
      *(uint2*)&Yb[(size_t)(i * 64 + ty * 4 + r) * 34 + tx * 2] = u;
      macc[0] += yv[r][0] * yv[r][0];
      macc[1] += yv[r][1] * yv[r][1];
      macc[2] += yv[r][2] * yv[r][2];
      macc[3] += yv[r][3] * yv[r][3];
    }
  }
  // reduce maha over ty (in-wave: ty groups are lane+16/+32) then across waves
#pragma unroll
  for (int j = 0; j < 4; ++j) {
    macc[j] += __shfl_down(macc[j], 32, 64);
    macc[j] += __shfl_down(macc[j], 16, 64);
  }
  int lane = tid & 63, w = tid >> 6;
  if (lane < 16) *(float4*)&Red[w * 64 + lane * 4] = make_float4(macc[0], macc[1], macc[2], macc[3]);
  if (w == 0) {
    float v = ldacc;
    v += __shfl_down(v, 32, 64);
    v += __shfl_down(v, 16, 64);
    v += __shfl_down(v, 8, 64);
    v += __shfl_down(v, 4, 64);
    v += __shfl_down(v, 2, 64);
    v += __shfl_down(v, 1, 64);
    if (lane == 0) Red[256] = v;  // sum log(invD_kk) = -0.5*logdet
  }
  __syncthreads();
  if (tid < 64) {
    float mh = Red[tid] + Red[64 + tid] + Red[128 + tid] + Red[192 + tid];
    float S = Red[256];
    out[(size_t)(b0 + tid) * 256 + s] = -0.5f * (LOG2PI_D - 2.0f * S + mh);
  }
}

extern "C" void kernel_launch(void* const* d_in, const int* in_sizes, int n_in,
                              void* d_out, int out_size, void* d_ws, size_t ws_size,
                              hipStream_t stream) {
  const float* x = (const float*)d_in[0];   // (1024,256)
  const float* mu = (const float*)d_in[1];  // (256,1,256)
  const float* sp = (const float*)d_in[2];  // (256,1,256,256)
  float* out = (float*)d_out;
  float* L = (float*)d_ws;  // 64 MB

  const int panel_lds = 4 * 64 * 68 * 4;                      // 69,632
  const int trail_lds = 2 * 64 * 68 * 4;                      // 34,816
  const int maha_lds = (256 * 34 + 64 * 68 + 260) * 4;        // 53,264
  (void)hipFuncSetAttribute((const void*)k_panel,
                            hipFuncAttributeMaxDynamicSharedMemorySize, panel_lds);
  (void)hipFuncSetAttribute((const void*)k_trail,
                            hipFuncAttributeMaxDynamicSharedMemorySize, trail_lds);
  (void)hipFuncSetAttribute((const void*)k_maha,
                            hipFuncAttributeMaxDynamicSharedMemorySize, maha_lds);

  k_ridge<<<256, 256, 0, stream>>>(sp, L);
  k_gram<<<dim3(3, 256), 256, 0, stream>>>(sp, L);
  const int npairs[4] = {6, 3, 1, 0};
  for (int kb = 0; kb < 4; ++kb) {
    k_panel<<<256, 256, panel_lds, stream>>>(L, kb);
    if (npairs[kb])
      k_trail<<<dim3(npairs[kb], 256), 256, trail_lds, stream>>>(L, kb);
  }
  k_maha<<<dim3(16, 256), 256, maha_lds, stream>>>(x, mu, L, out);
}